// Round 11
// baseline (133.420 us; speedup 1.0000x reference)
//
#include <hip/hip_runtime.h>

#define BATCH 200000
#define DD 16
#define LIB 969          // 1 + 16 + 136 + 816
#define KPAD 1024        // features padded to 16 chunks of 64 (pad coeff rows = 0)
#define CHUNK 64         // features per LDS chunk
#define NCHUNK 16
#define A_STRIDE 144     // bytes/row/chunk: 64*2 + 16 pad (odd multiple of 16B)
#define A_BYTES (256 * A_STRIDE)        // 36864 B static LDS -> 4 blocks/CU by LDS

typedef short short8 __attribute__((ext_vector_type(8)));
typedef float f32x4 __attribute__((ext_vector_type(4)));

// ---- compile-time feature enumeration (R4-verified) ----
struct FIdx { int a, b, c; };
constexpr FIdx feat_idx(int f) {
  if (f == 0) return FIdx{-1, -1, -1};               // constant 1
  if (f <= DD) return FIdx{f - 1, -1, -1};           // linear
  if (f < 1 + DD + DD * (DD + 1) / 2) {              // quadratic, lex (i<=j)
    int t = f - 1 - DD;
    for (int i = 0; i < DD; ++i) {
      if (t < DD - i) return FIdx{i, i + t, -1};
      t -= DD - i;
    }
  }
  if (f < LIB) {                                     // cubic, lex (i<=j<=k)
    int t = f - (1 + DD + DD * (DD + 1) / 2);
    for (int i = 0; i < DD; ++i)
      for (int j = i; j < DD; ++j) {
        if (t < DD - j) return FIdx{i, j, j + t};
        t -= DD - j;
      }
  }
  return FIdx{-2, -2, -2};                           // padding -> 0
}

template <int F>
__device__ __forceinline__ float fval(const float* z) {
  constexpr FIdx t = feat_idx(F);
  if constexpr (t.a == -2) return 0.0f;
  else if constexpr (t.a == -1) return 1.0f;
  else if constexpr (t.b == -1) return z[t.a];
  else if constexpr (t.c == -1) return z[t.a] * z[t.b];
  else return (z[t.a] * z[t.b]) * z[t.c];            // prefix CSE across k
}

// f32 -> bf16 RNE, two at a time, pure integer bit math (R4-verified path).
__device__ __forceinline__ unsigned int pk_bf16(float a, float b) {
  unsigned int ua = __builtin_bit_cast(unsigned int, a);
  unsigned int ub = __builtin_bit_cast(unsigned int, b);
  ua += 0x7fffu + ((ua >> 16) & 1u);   // round-to-nearest-even (finite inputs)
  ub += 0x7fffu + ((ub >> 16) & 1u);
  return (ua >> 16) | (ub & 0xffff0000u);
}

// 8 features -> 8 bf16 -> one ds_write_b128.  dst aliases the LDS tile that
// MFMA fragments are read from -> NO __restrict__ (R3 lesson).
template <int F>
__device__ __forceinline__ void emit8(const float* z, char* dst) {
  float a0 = fval<F + 0>(z), a1 = fval<F + 1>(z), a2 = fval<F + 2>(z), a3 = fval<F + 3>(z);
  float a4 = fval<F + 4>(z), a5 = fval<F + 5>(z), a6 = fval<F + 6>(z), a7 = fval<F + 7>(z);
  uint4 v;
  v.x = pk_bf16(a0, a1);
  v.y = pk_bf16(a2, a3);
  v.z = pk_bf16(a4, a5);
  v.w = pk_bf16(a6, a7);
  *(uint4*)dst = v;
}

// One 64-feature chunk: produce (own row, wave-private LDS slice) then consume.
// B-coeff fragments come STRAIGHT FROM GLOBAL (L2/L3-resident 32 KB table) --
// identical claimed k-addressing to R4's B-LDS path, so the R4 certificate holds.
template <int C>
__device__ __forceinline__ void chunk_step(const float* z,
                                           char* aRow,
                                           const char* aRead,
                                           const unsigned short* btl,
                                           f32x4 (&acc)[4]) {
  emit8<C * CHUNK + 0>(z, aRow + 0);
  emit8<C * CHUNK + 8>(z, aRow + 16);
  emit8<C * CHUNK + 16>(z, aRow + 32);
  emit8<C * CHUNK + 24>(z, aRow + 48);
  emit8<C * CHUNK + 32>(z, aRow + 64);
  emit8<C * CHUNK + 40>(z, aRow + 80);
  emit8<C * CHUNK + 48>(z, aRow + 96);
  emit8<C * CHUNK + 56>(z, aRow + 112);
  asm volatile("" ::: "memory");   // compile-time fence: LDS writes above, reads below
#pragma unroll
  for (int t = 0; t < CHUNK / 32; ++t) {
    short8 bf = *(const short8*)(btl + C * 64 + t * 32);   // global, imm-offset folds
#pragma unroll
    for (int m = 0; m < 4; ++m) {
      short8 af = *(const short8*)(aRead + m * 16 * A_STRIDE + t * 64);
      acc[m] = __builtin_amdgcn_mfma_f32_16x16x32_bf16(af, bf, acc[m], 0, 0, 0);
    }
  }
}

template <int C>
struct Chunks {
  static __device__ __forceinline__ void run(const float* z, char* aRow, const char* aRead,
                                             const unsigned short* btl, f32x4 (&acc)[4]) {
    chunk_step<C>(z, aRow, aRead, btl, acc);
    Chunks<C + 1>::run(z, aRow, aRead, btl, acc);
  }
};
template <>
struct Chunks<NCHUNK> {
  static __device__ __forceinline__ void run(const float*, char*, const char*,
                                             const unsigned short*, f32x4 (&)[4]) {}
};

// ---- prep (R4-verified): bt[col][k] = coeff_full[k][col] bf16, k<969 else 0 ----
__global__ __launch_bounds__(256) void prep_bt(const float* __restrict__ coeff,
                                               const float* __restrict__ fixedv,
                                               const unsigned char* __restrict__ mask,
                                               unsigned short* __restrict__ bt) {
  int e = blockIdx.x * 256 + threadIdx.x;   // 0 .. 16383
  if (e >= DD * KPAD) return;
  int col = e >> 10, k = e & (KPAD - 1);
  float v = 0.0f;
  if (k < LIB) {
    int idx = k * DD + col;
    v = mask[idx] ? fixedv[idx] : coeff[idx];
  }
  unsigned int u = __builtin_bit_cast(unsigned int, v);
  u += 0x7fffu + ((u >> 16) & 1u);
  bt[e] = (unsigned short)(u >> 16);
}

__global__ __launch_bounds__(256, 3) void sindy_mfma(const float* __restrict__ z,
                                                     const unsigned short* __restrict__ bt,
                                                     float* __restrict__ out) {
  __shared__ alignas(16) char aLds[A_BYTES];           // 36864 B (A tile only)
  const int tid = threadIdx.x;
  const int lane = tid & 63;
  const int w = tid >> 6;
  const long long row = (long long)blockIdx.x * 256 + tid;

  float zr[16];
  if (row < BATCH) {
    const float4* zp = (const float4*)(z + row * DD);
    float4 z0 = zp[0], z1 = zp[1], z2 = zp[2], z3 = zp[3];
    zr[0] = z0.x; zr[1] = z0.y; zr[2] = z0.z; zr[3] = z0.w;
    zr[4] = z1.x; zr[5] = z1.y; zr[6] = z1.z; zr[7] = z1.w;
    zr[8] = z2.x; zr[9] = z2.y; zr[10] = z2.z; zr[11] = z2.w;
    zr[12] = z3.x; zr[13] = z3.y; zr[14] = z3.z; zr[15] = z3.w;
  } else {
#pragma unroll
    for (int i = 0; i < 16; ++i) zr[i] = 0.0f;
  }

  f32x4 acc[4] = {f32x4{0.f, 0.f, 0.f, 0.f}, f32x4{0.f, 0.f, 0.f, 0.f},
                  f32x4{0.f, 0.f, 0.f, 0.f}, f32x4{0.f, 0.f, 0.f, 0.f}};
  char* aRow = aLds + tid * A_STRIDE;                                   // producer: own row
  const char* aRead = aLds + (w * 64 + (lane & 15)) * A_STRIDE + (lane >> 4) * 16;
  // B (coeff) per-lane global base: col = lane&15, k-group = lane>>4 (shorts)
  const unsigned short* btl = bt + (lane & 15) * KPAD + (lane >> 4) * 8;

  Chunks<0>::run(zr, aRow, aRead, btl, acc);

  // C/D layout (R4-verified): col = lane&15, row = 4*(lane>>4)+q
  const long long obase = (long long)blockIdx.x * 256 + w * 64;
  const int col = lane & 15;
#pragma unroll
  for (int m = 0; m < 4; ++m) {
#pragma unroll
    for (int q = 0; q < 4; ++q) {
      long long r = obase + m * 16 + (lane >> 4) * 4 + q;
      if (r < BATCH) out[r * DD + col] = acc[m][q];
    }
  }
}

extern "C" void kernel_launch(void* const* d_in, const int* in_sizes, int n_in,
                              void* d_out, int out_size, void* d_ws, size_t ws_size,
                              hipStream_t stream) {
  const float* z = (const float*)d_in[0];
  const float* coeff = (const float*)d_in[1];
  const float* fixedv = (const float*)d_in[2];
  const unsigned char* mask = (const unsigned char*)d_in[3];
  float* out = (float*)d_out;
  unsigned short* bt = (unsigned short*)d_ws;   // 16*1024*2 = 32768 B

  prep_bt<<<(DD * KPAD + 255) / 256, 256, 0, stream>>>(coeff, fixedv, mask, bt);

  const int nblk = (BATCH + 255) / 256;   // 782
  sindy_mfma<<<nblk, 256, 0, stream>>>(z, bt, out);
}